// Round 1
// baseline (1248.612 us; speedup 1.0000x reference)
//
#include <hip/hip_runtime.h>

#define BATCH 64
#define KSLOT 64
#define DDIM  128
#define HDIM  128
#define TTYPE 4
#define NSLOT (BATCH*KSLOT)
#define EPSLN 1e-5f

// ---------- helpers ----------
__device__ __forceinline__ float blockReduce128(float v, float* sbuf) {
    // 128 threads = 2 waves of 64
    #pragma unroll
    for (int off = 32; off > 0; off >>= 1) v += __shfl_down(v, off, 64);
    int wid = threadIdx.x >> 6;
    if ((threadIdx.x & 63) == 0) sbuf[wid] = v;
    __syncthreads();
    float r = sbuf[0] + sbuf[1];
    __syncthreads();
    return r;
}

// ---------- K_A1: per-slot LN + f_self MLP -> dself ----------
__global__ __launch_bounds__(128) void k_self(
        const float* __restrict__ hin,
        const float* __restrict__ ls_g, const float* __restrict__ ls_b,
        const float* __restrict__ ws1, const float* __restrict__ bs1,
        const float* __restrict__ ws2, const float* __restrict__ bs2,
        float* __restrict__ dself) {
    __shared__ __align__(16) float hsn[DDIM];
    __shared__ __align__(16) float t1[HDIM];
    __shared__ float red[2];
    int s = blockIdx.x;
    int tid = threadIdx.x;
    float hv = hin[s*DDIM + tid];
    float sum = blockReduce128(hv, red);
    float mu = sum * (1.0f/DDIM);
    float dv = hv - mu;
    float var = blockReduce128(dv*dv, red) * (1.0f/DDIM);
    float rs = rsqrtf(var + EPSLN);
    hsn[tid] = dv*rs*ls_g[tid] + ls_b[tid];
    __syncthreads();
    float acc = bs1[tid];
    for (int d = 0; d < DDIM; d++) acc += hsn[d]*ws1[d*HDIM + tid];
    t1[tid] = fmaxf(acc, 0.f);
    __syncthreads();
    float acc2 = bs2[tid];
    for (int d = 0; d < HDIM; d++) acc2 += t1[d]*ws2[d*DDIM + tid];
    dself[s*DDIM + tid] = acc2;
}

// ---------- K_A2: A[t,s,o] = h[s]@wi1[t][:D], C[t,s,o] = h[s]@wi1[t][D:] + bi1 ----------
__global__ __launch_bounds__(256) void k_proj(
        const float* __restrict__ hin,
        const float* __restrict__ wi1, const float* __restrict__ bi1,
        float* __restrict__ At, float* __restrict__ Ct) {
    __shared__ __align__(16) float hs8[8*DDIM];   // 8 slots
    int g = blockIdx.x;          // 512 blocks
    int tid = threadIdx.x;
    int s0 = g*8;
    {
        const float4* src = (const float4*)(hin + (size_t)s0*DDIM);
        float4* dst = (float4*)hs8;
        dst[tid] = src[tid];     // 256 * float4 = 1024 floats
    }
    __syncthreads();
    #pragma unroll
    for (int cc = 0; cc < 4; cc++) {
        int c = tid + cc*256;        // 0..1023
        int th = c >> 7;             // tau*2 + half
        int o  = c & 127;
        const float* wp = wi1 + (size_t)th*(DDIM*HDIM) + o;  // elem d at wp[d*HDIM]
        float acc[8];
        #pragma unroll
        for (int s = 0; s < 8; s++) acc[s] = 0.f;
        for (int d = 0; d < DDIM; d++) {
            float wv = wp[d*HDIM];
            #pragma unroll
            for (int s = 0; s < 8; s++) acc[s] += hs8[s*DDIM + d]*wv;
        }
        int tau = th >> 1;
        if ((th & 1) == 0) {
            #pragma unroll
            for (int s = 0; s < 8; s++)
                At[((size_t)tau*NSLOT + s0 + s)*HDIM + o] = acc[s];
        } else {
            float bv = bi1[tau*HDIM + o];
            #pragma unroll
            for (int s = 0; s < 8; s++)
                Ct[((size_t)tau*NSLOT + s0 + s)*HDIM + o] = acc[s] + bv;
        }
    }
}

// ---------- K_B: the big pair kernel ----------
// block = (b,tau); loops senders i two at a time.
// x1 = relu(A[i] + C[j]); x2 = relu(x1@wi2 + bi2); y[j] += w[i,j]*x2; wsum[j] += w.
#define FMA8(ACC, AV, W0, W1) \
    ACC[0] += (AV)*(W0).x; ACC[1] += (AV)*(W0).y; ACC[2] += (AV)*(W0).z; ACC[3] += (AV)*(W0).w; \
    ACC[4] += (AV)*(W1).x; ACC[5] += (AV)*(W1).y; ACC[6] += (AV)*(W1).z; ACC[7] += (AV)*(W1).w;

__global__ __launch_bounds__(256) void k_pair(
        const float* __restrict__ At, const float* __restrict__ Ct,
        const float* __restrict__ wi2, const float* __restrict__ bi2,
        const float* __restrict__ ep, const float* __restrict__ et,
        float* __restrict__ y, float* __restrict__ wsum) {
    __shared__ __align__(16) float wi2s[HDIM*HDIM];        // 64 KB, [d*128+o]
    __shared__ __align__(16) float X1[2][KSLOT][DDIM+4];   // 67.6 KB (pad 132 keeps 16B align + bank spread)
    __shared__ __align__(16) float As[2][DDIM];
    __shared__ float wrow[2][KSLOT];
    int bx = blockIdx.x;
    int b = bx >> 2, tau = bx & 3;
    int tid = threadIdx.x;
    int jg = tid >> 4, og = tid & 15;    // 16 j-groups x 16 o-groups

    {   // stage wi2[tau]
        const float4* wsrc = (const float4*)(wi2 + (size_t)tau*HDIM*HDIM);
        float4* wdst = (float4*)wi2s;
        for (int k = tid; k < HDIM*HDIM/4; k += 256) wdst[k] = wsrc[k];
    }
    float bi[8];
    #pragma unroll
    for (int c = 0; c < 8; c++) bi[c] = bi2[tau*HDIM + og*8 + c];
    float yacc[4][8];
    #pragma unroll
    for (int r = 0; r < 4; r++)
        #pragma unroll
        for (int c = 0; c < 8; c++) yacc[r][c] = 0.f;
    float wsacc[4] = {0.f,0.f,0.f,0.f};

    const float* abase = At + ((size_t)tau*NSLOT + b*KSLOT)*HDIM;
    const float* cbase = Ct + ((size_t)tau*NSLOT + b*KSLOT)*HDIM;
    const float* epb = ep + (size_t)b*KSLOT*KSLOT;
    const float* etb = et + (size_t)b*KSLOT*KSLOT*TTYPE + tau;
    __syncthreads();

    for (int i0 = 0; i0 < KSLOT; i0 += 2) {
        // stage A rows for i0, i0+1 and the w rows
        if (tid < 64) {
            int ii = tid >> 5, q = tid & 31;
            ((float4*)As[ii])[q] = ((const float4*)(abase + (size_t)(i0+ii)*HDIM))[q];
        } else if (tid < 192) {
            int k = tid - 64;            // 0..127
            int ii = k >> 6, j = k & 63;
            int i = i0 + ii;
            wrow[ii][j] = epb[i*KSLOT + j] * etb[(size_t)(i*KSLOT + j)*TTYPE];
        }
        __syncthreads();
        {   // build X1 for both i: thread -> j = tid>>2, d0 = (tid&3)*32
            int j = tid >> 2, d0 = (tid & 3) * 32;
            const float4* crow = (const float4*)(cbase + (size_t)j*HDIM + d0);
            #pragma unroll
            for (int q = 0; q < 8; q++) {
                float4 cv = crow[q];
                float4 av0 = *(const float4*)&As[0][d0 + q*4];
                float4 av1 = *(const float4*)&As[1][d0 + q*4];
                float4 x0, x1v;
                x0.x = fmaxf(av0.x + cv.x, 0.f);  x0.y = fmaxf(av0.y + cv.y, 0.f);
                x0.z = fmaxf(av0.z + cv.z, 0.f);  x0.w = fmaxf(av0.w + cv.w, 0.f);
                x1v.x = fmaxf(av1.x + cv.x, 0.f); x1v.y = fmaxf(av1.y + cv.y, 0.f);
                x1v.z = fmaxf(av1.z + cv.z, 0.f); x1v.w = fmaxf(av1.w + cv.w, 0.f);
                *(float4*)&X1[0][j][d0 + q*4] = x0;
                *(float4*)&X1[1][j][d0 + q*4] = x1v;
            }
        }
        __syncthreads();
        float acc0[4][8], acc1[4][8];
        #pragma unroll
        for (int r = 0; r < 4; r++)
            #pragma unroll
            for (int c = 0; c < 8; c++) { acc0[r][c] = bi[c]; acc1[r][c] = bi[c]; }
        #pragma unroll 2
        for (int d = 0; d < DDIM; d += 4) {
            float4 a0[4], a1[4];
            #pragma unroll
            for (int r = 0; r < 4; r++) {
                a0[r] = *(const float4*)&X1[0][jg*4+r][d];
                a1[r] = *(const float4*)&X1[1][jg*4+r][d];
            }
            #pragma unroll
            for (int dd = 0; dd < 4; dd++) {
                const float* wp = &wi2s[(d+dd)*HDIM + og*8];
                float4 w0 = *(const float4*)wp;
                float4 w1 = *(const float4*)(wp+4);
                #pragma unroll
                for (int r = 0; r < 4; r++) {
                    float av0 = ((const float*)&a0[r])[dd];
                    float av1 = ((const float*)&a1[r])[dd];
                    FMA8(acc0[r], av0, w0, w1)
                    FMA8(acc1[r], av1, w0, w1)
                }
            }
        }
        #pragma unroll
        for (int r = 0; r < 4; r++) {
            float w0v = wrow[0][jg*4+r], w1v = wrow[1][jg*4+r];
            wsacc[r] += w0v + w1v;
            #pragma unroll
            for (int c = 0; c < 8; c++)
                yacc[r][c] += w0v*fmaxf(acc0[r][c],0.f) + w1v*fmaxf(acc1[r][c],0.f);
        }
        __syncthreads();
    }
    float* yb = y + ((size_t)tau*NSLOT + b*KSLOT)*HDIM;
    #pragma unroll
    for (int r = 0; r < 4; r++) {
        int j = jg*4 + r;
        float4 v0, v1;
        v0.x = yacc[r][0]; v0.y = yacc[r][1]; v0.z = yacc[r][2]; v0.w = yacc[r][3];
        v1.x = yacc[r][4]; v1.y = yacc[r][5]; v1.z = yacc[r][6]; v1.w = yacc[r][7];
        *(float4*)&yb[(size_t)j*HDIM + og*8]     = v0;
        *(float4*)&yb[(size_t)j*HDIM + og*8 + 4] = v1;
    }
    if (og == 0) {
        #pragma unroll
        for (int r = 0; r < 4; r++)
            wsum[(size_t)tau*NSLOT + b*KSLOT + jg*4 + r] = wsacc[r];
    }
}

// ---------- K_C: delta_inter = sum_tau(y@wi3 + wsum*bi3); combined; LN; update MLP; h += ----------
__global__ __launch_bounds__(128) void k_update(
        const float* __restrict__ hin, const float* __restrict__ dself,
        const float* __restrict__ y, const float* __restrict__ wsum,
        const float* __restrict__ wi3, const float* __restrict__ bi3,
        const float* __restrict__ lu_g, const float* __restrict__ lu_b,
        const float* __restrict__ wu1, const float* __restrict__ bu1,
        const float* __restrict__ wu2, const float* __restrict__ bu2,
        float* __restrict__ hout) {
    __shared__ __align__(16) float ys[TTYPE][HDIM];
    __shared__ __align__(16) float comb[2*DDIM];
    __shared__ __align__(16) float u1[HDIM];
    __shared__ float red[2];
    __shared__ float wsv[TTYPE];
    int s = blockIdx.x, tid = threadIdx.x;
    #pragma unroll
    for (int tau = 0; tau < TTYPE; tau++)
        ys[tau][tid] = y[((size_t)tau*NSLOT + s)*HDIM + tid];
    if (tid < TTYPE) wsv[tid] = wsum[(size_t)tid*NSLOT + s];
    __syncthreads();
    float di = 0.f;
    #pragma unroll
    for (int tau = 0; tau < TTYPE; tau++) {
        float a = wsv[tau] * bi3[tau*DDIM + tid];
        const float* wp = wi3 + (size_t)tau*HDIM*DDIM + tid;
        for (int d = 0; d < HDIM; d++) a += ys[tau][d]*wp[d*DDIM];
        di += a;
    }
    float hv = hin[(size_t)s*DDIM + tid];
    float v0 = hv + dself[(size_t)s*DDIM + tid];
    float v1 = di;
    comb[tid] = v0;
    comb[DDIM + tid] = v1;
    __syncthreads();
    float sum = blockReduce128(v0 + v1, red);
    float mu = sum * (1.0f/(2*DDIM));
    float d0 = v0 - mu, d1 = v1 - mu;
    float var = blockReduce128(d0*d0 + d1*d1, red) * (1.0f/(2*DDIM));
    float rs = rsqrtf(var + EPSLN);
    comb[tid]        = d0*rs*lu_g[tid] + lu_b[tid];
    comb[DDIM + tid] = d1*rs*lu_g[DDIM + tid] + lu_b[DDIM + tid];
    __syncthreads();
    float a1 = bu1[tid];
    for (int d = 0; d < 2*DDIM; d++) a1 += comb[d]*wu1[d*HDIM + tid];
    u1[tid] = fmaxf(a1, 0.f);
    __syncthreads();
    float a2 = bu2[tid];
    for (int d = 0; d < HDIM; d++) a2 += u1[d]*wu2[d*DDIM + tid];
    hout[(size_t)s*DDIM + tid] = hv + a2;
}

// ---------- launch ----------
extern "C" void kernel_launch(void* const* d_in, const int* in_sizes, int n_in,
                              void* d_out, int out_size, void* d_ws, size_t ws_size,
                              hipStream_t stream) {
    const float* slots = (const float*)d_in[0];
    const float* ep    = (const float*)d_in[1];
    const float* et    = (const float*)d_in[2];
    const float* ls_g  = (const float*)d_in[3];
    const float* ls_b  = (const float*)d_in[4];
    const float* ws1   = (const float*)d_in[5];
    const float* bs1   = (const float*)d_in[6];
    const float* ws2   = (const float*)d_in[7];
    const float* bs2   = (const float*)d_in[8];
    const float* wi1   = (const float*)d_in[9];
    const float* bi1   = (const float*)d_in[10];
    const float* wi2   = (const float*)d_in[11];
    const float* bi2   = (const float*)d_in[12];
    const float* wi3   = (const float*)d_in[13];
    const float* bi3   = (const float*)d_in[14];
    const float* lu_g  = (const float*)d_in[15];
    const float* lu_b  = (const float*)d_in[16];
    const float* wu1   = (const float*)d_in[17];
    const float* bu1   = (const float*)d_in[18];
    const float* wu2   = (const float*)d_in[19];
    const float* bu2   = (const float*)d_in[20];
    float* out = (float*)d_out;

    float* ws = (float*)d_ws;
    float* h_buf = ws;                    ws += (size_t)NSLOT*DDIM;          // 524288
    float* dself = ws;                    ws += (size_t)NSLOT*DDIM;
    float* At    = ws;                    ws += (size_t)TTYPE*NSLOT*HDIM;    // 2M
    float* Ct    = ws;                    ws += (size_t)TTYPE*NSLOT*HDIM;
    float* yb    = ws;                    ws += (size_t)TTYPE*NSLOT*HDIM;
    float* wsumb = ws;                    ws += (size_t)TTYPE*NSLOT;

    for (int mp = 0; mp < 2; mp++) {
        const float* hin = (mp == 0) ? slots : h_buf;
        float* hout = (mp == 0) ? h_buf : out;
        k_self<<<NSLOT, 128, 0, stream>>>(hin, ls_g, ls_b, ws1, bs1, ws2, bs2, dself);
        k_proj<<<NSLOT/8, 256, 0, stream>>>(hin, wi1, bi1, At, Ct);
        k_pair<<<BATCH*TTYPE, 256, 0, stream>>>(At, Ct, wi2, bi2, ep, et, yb, wsumb);
        k_update<<<NSLOT, 128, 0, stream>>>(hin, dself, yb, wsumb, wi3, bi3,
                                            lu_g, lu_b, wu1, bu1, wu2, bu2, hout);
    }
}

// Round 2
// 400.809 us; speedup vs baseline: 3.1152x; 3.1152x over previous
//
#include <hip/hip_runtime.h>
#include <hip/hip_fp16.h>

#define BATCH 64
#define KSLOT 64
#define DDIM  128
#define HDIM  128
#define TTYPE 4
#define NSLOT (BATCH*KSLOT)
#define EPSLN 1e-5f

typedef _Float16 v8h __attribute__((ext_vector_type(8)));
typedef float    v4f __attribute__((ext_vector_type(4)));

// ---------- helpers ----------
__device__ __forceinline__ float blockReduce128(float v, float* sbuf) {
    #pragma unroll
    for (int off = 32; off > 0; off >>= 1) v += __shfl_down(v, off, 64);
    int wid = threadIdx.x >> 6;
    if ((threadIdx.x & 63) == 0) sbuf[wid] = v;
    __syncthreads();
    float r = sbuf[0] + sbuf[1];
    __syncthreads();
    return r;
}

// ---------- K_A1: per-slot LN + f_self MLP -> dself ----------
__global__ __launch_bounds__(128) void k_self(
        const float* __restrict__ hin,
        const float* __restrict__ ls_g, const float* __restrict__ ls_b,
        const float* __restrict__ ws1, const float* __restrict__ bs1,
        const float* __restrict__ ws2, const float* __restrict__ bs2,
        float* __restrict__ dself) {
    __shared__ __align__(16) float hsn[DDIM];
    __shared__ __align__(16) float t1[HDIM];
    __shared__ float red[2];
    int s = blockIdx.x;
    int tid = threadIdx.x;
    float hv = hin[s*DDIM + tid];
    float sum = blockReduce128(hv, red);
    float mu = sum * (1.0f/DDIM);
    float dv = hv - mu;
    float var = blockReduce128(dv*dv, red) * (1.0f/DDIM);
    float rs = rsqrtf(var + EPSLN);
    hsn[tid] = dv*rs*ls_g[tid] + ls_b[tid];
    __syncthreads();
    float acc = bs1[tid];
    for (int d = 0; d < DDIM; d++) acc += hsn[d]*ws1[d*HDIM + tid];
    t1[tid] = fmaxf(acc, 0.f);
    __syncthreads();
    float acc2 = bs2[tid];
    for (int d = 0; d < HDIM; d++) acc2 += t1[d]*ws2[d*DDIM + tid];
    dself[s*DDIM + tid] = acc2;
}

// ---------- K_A2: A[t,s,o] = h[s]@wi1[t][:D] (f16), C[t,s,o] = h[s]@wi1[t][D:] + bi1 (f16) ----------
__global__ __launch_bounds__(256) void k_proj(
        const float* __restrict__ hin,
        const float* __restrict__ wi1, const float* __restrict__ bi1,
        __half* __restrict__ At, __half* __restrict__ Ct) {
    __shared__ __align__(16) float hs8[8*DDIM];   // 8 slots
    int g = blockIdx.x;          // 512 blocks
    int tid = threadIdx.x;
    int s0 = g*8;
    {
        const float4* src = (const float4*)(hin + (size_t)s0*DDIM);
        float4* dst = (float4*)hs8;
        dst[tid] = src[tid];
    }
    __syncthreads();
    #pragma unroll
    for (int cc = 0; cc < 4; cc++) {
        int c = tid + cc*256;        // 0..1023
        int th = c >> 7;             // tau*2 + half
        int o  = c & 127;
        const float* wp = wi1 + (size_t)th*(DDIM*HDIM) + o;
        float acc[8];
        #pragma unroll
        for (int s = 0; s < 8; s++) acc[s] = 0.f;
        for (int d = 0; d < DDIM; d++) {
            float wv = wp[d*HDIM];
            #pragma unroll
            for (int s = 0; s < 8; s++) acc[s] += hs8[s*DDIM + d]*wv;
        }
        int tau = th >> 1;
        if ((th & 1) == 0) {
            #pragma unroll
            for (int s = 0; s < 8; s++)
                At[((size_t)tau*NSLOT + s0 + s)*HDIM + o] = __float2half(acc[s]);
        } else {
            float bv = bi1[tau*HDIM + o];
            #pragma unroll
            for (int s = 0; s < 8; s++)
                Ct[((size_t)tau*NSLOT + s0 + s)*HDIM + o] = __float2half(acc[s] + bv);
        }
    }
}

// ---------- K_B: MFMA pair kernel ----------
// block = (b,tau), 256 threads = 4 waves. wave = j-tile (16 j's).
// Per sender i: x1frag = relu(A[i]+C[j]) built in-register (f16),
// X2 = x1 @ wi2T via mfma_f32_16x16x32_f16 (8 o-tiles x 4 k-steps),
// yacc[j,o] += w[i,j] * relu(X2 + bi2).  No syncthreads in the i-loop.
#define LROW 136   // f16 row stride: 272 B, 16B aligned, 2-way bank alias (free)

__global__ __launch_bounds__(256, 1) void k_pair(
        const __half* __restrict__ At, const __half* __restrict__ Ct,
        const float* __restrict__ wi2, const float* __restrict__ bi2,
        const float* __restrict__ ep, const float* __restrict__ et,
        float* __restrict__ y, float* __restrict__ wsum) {
    __shared__ __align__(16) _Float16 w2T[HDIM*LROW];  // [o][d] 34816 B
    __shared__ __align__(16) _Float16 Cs[KSLOT*LROW];  // [j][d] 17408 B
    __shared__ __align__(16) _Float16 As[KSLOT*LROW];  // [i][d] 17408 B
    __shared__ __align__(16) float    wS[KSLOT*KSLOT]; // [i][j] 16384 B

    int bx = blockIdx.x;
    int b = bx >> 2, tau = bx & 3;
    int tid = threadIdx.x;
    int lane = tid & 63;
    int jt   = tid >> 6;          // wave id = j-tile
    int quad = lane >> 4;
    int n    = lane & 15;

    // ---- stage wi2^T as f16 [o][d] ----
    {
        const float* wsrc = wi2 + (size_t)tau*HDIM*HDIM;
        for (int idx = tid; idx < HDIM*(HDIM/2); idx += 256) {
            int dp = idx >> 7;          // d-pair
            int o  = idx & 127;
            int d  = dp*2;
            float a0 = wsrc[(size_t)d*HDIM + o];
            float a1 = wsrc[(size_t)(d+1)*HDIM + o];
            __half2 p = __floats2half2_rn(a0, a1);
            *(__half2*)&w2T[o*LROW + d] = p;
        }
    }
    // ---- stage C and A rows (already f16 in global) ----
    {
        const __half* cb = Ct + ((size_t)tau*NSLOT + b*KSLOT)*HDIM;
        const __half* ab = At + ((size_t)tau*NSLOT + b*KSLOT)*HDIM;
        for (int u = tid; u < KSLOT*16; u += 256) {   // 16 units of 8 f16 per row
            int j = u >> 4, dblk = (u & 15)*8;
            *(v8h*)&Cs[j*LROW + dblk] = *(const v8h*)&cb[(size_t)j*HDIM + dblk];
            *(v8h*)&As[j*LROW + dblk] = *(const v8h*)&ab[(size_t)j*HDIM + dblk];
        }
    }
    // ---- stage w[i][j] = ep * et[...,tau] ----
    {
        const float* epb = ep + (size_t)b*KSLOT*KSLOT;
        const float* etb = et + (size_t)b*KSLOT*KSLOT*TTYPE + tau;
        for (int idx = tid; idx < KSLOT*KSLOT; idx += 256) {
            wS[idx] = epb[idx] * etb[(size_t)idx*TTYPE];
        }
    }
    __syncthreads();

    // ---- preload i-invariant fragments ----
    v8h bfrag[8][4];     // [o-tile][k-step]
    #pragma unroll
    for (int ot = 0; ot < 8; ot++)
        #pragma unroll
        for (int ks = 0; ks < 4; ks++)
            bfrag[ot][ks] = *(const v8h*)&w2T[(ot*16 + n)*LROW + ks*32 + quad*8];
    v8h cfrag[4];
    #pragma unroll
    for (int ks = 0; ks < 4; ks++)
        cfrag[ks] = *(const v8h*)&Cs[(jt*16 + n)*LROW + ks*32 + quad*8];
    float biasv[8];
    #pragma unroll
    for (int ot = 0; ot < 8; ot++) biasv[ot] = bi2[tau*HDIM + ot*16 + n];

    v4f yacc[8];
    #pragma unroll
    for (int ot = 0; ot < 8; ot++) yacc[ot] = (v4f){0.f,0.f,0.f,0.f};
    float wsacc[4] = {0.f,0.f,0.f,0.f};

    const v8h zero8 = {0,0,0,0,0,0,0,0};

    // prefetch i=0
    v8h aN[4]; float wvN[4];
    #pragma unroll
    for (int ks = 0; ks < 4; ks++) aN[ks] = *(const v8h*)&As[0*LROW + ks*32 + quad*8];
    #pragma unroll
    for (int r = 0; r < 4; r++) wvN[r] = wS[0*KSLOT + jt*16 + quad*4 + r];

    for (int i = 0; i < KSLOT; ++i) {
        v8h a[4]; float wv[4];
        #pragma unroll
        for (int ks = 0; ks < 4; ks++) a[ks] = aN[ks];
        #pragma unroll
        for (int r = 0; r < 4; r++) wv[r] = wvN[r];
        if (i < KSLOT-1) {      // prefetch next sender
            #pragma unroll
            for (int ks = 0; ks < 4; ks++)
                aN[ks] = *(const v8h*)&As[(i+1)*LROW + ks*32 + quad*8];
            #pragma unroll
            for (int r = 0; r < 4; r++) wvN[r] = wS[(i+1)*KSLOT + jt*16 + quad*4 + r];
        }
        // build X1 fragments: relu(A[i] + C[j]) in f16
        v8h x1[4];
        #pragma unroll
        for (int ks = 0; ks < 4; ks++)
            x1[ks] = __builtin_elementwise_max(a[ks] + cfrag[ks], zero8);
        // MFMA + epilogue per o-tile
        #pragma unroll
        for (int ot = 0; ot < 8; ot++) {
            v4f acc = (v4f){biasv[ot], biasv[ot], biasv[ot], biasv[ot]};
            #pragma unroll
            for (int ks = 0; ks < 4; ks++)
                acc = __builtin_amdgcn_mfma_f32_16x16x32_f16(x1[ks], bfrag[ot][ks], acc, 0, 0, 0);
            #pragma unroll
            for (int r = 0; r < 4; r++)
                yacc[ot][r] = fmaf(wv[r], fmaxf(acc[r], 0.f), yacc[ot][r]);
        }
        #pragma unroll
        for (int r = 0; r < 4; r++) wsacc[r] += wv[r];
    }

    // ---- write y (fp32) and wsum ----
    float* yb = y + ((size_t)tau*NSLOT + b*KSLOT)*HDIM;
    #pragma unroll
    for (int r = 0; r < 4; r++) {
        int j = jt*16 + quad*4 + r;
        #pragma unroll
        for (int ot = 0; ot < 8; ot++)
            yb[(size_t)j*HDIM + ot*16 + n] = yacc[ot][r];
    }
    if (n == 0) {
        #pragma unroll
        for (int r = 0; r < 4; r++)
            wsum[(size_t)tau*NSLOT + b*KSLOT + jt*16 + quad*4 + r] = wsacc[r];
    }
}

// ---------- K_C: delta_inter = sum_tau(y@wi3 + wsum*bi3); combined; LN; update MLP; h += ----------
__global__ __launch_bounds__(128) void k_update(
        const float* __restrict__ hin, const float* __restrict__ dself,
        const float* __restrict__ y, const float* __restrict__ wsum,
        const float* __restrict__ wi3, const float* __restrict__ bi3,
        const float* __restrict__ lu_g, const float* __restrict__ lu_b,
        const float* __restrict__ wu1, const float* __restrict__ bu1,
        const float* __restrict__ wu2, const float* __restrict__ bu2,
        float* __restrict__ hout) {
    __shared__ __align__(16) float ys[TTYPE][HDIM];
    __shared__ __align__(16) float comb[2*DDIM];
    __shared__ __align__(16) float u1[HDIM];
    __shared__ float red[2];
    __shared__ float wsv[TTYPE];
    int s = blockIdx.x, tid = threadIdx.x;
    #pragma unroll
    for (int tau = 0; tau < TTYPE; tau++)
        ys[tau][tid] = y[((size_t)tau*NSLOT + s)*HDIM + tid];
    if (tid < TTYPE) wsv[tid] = wsum[(size_t)tid*NSLOT + s];
    __syncthreads();
    float di = 0.f;
    #pragma unroll
    for (int tau = 0; tau < TTYPE; tau++) {
        float a = wsv[tau] * bi3[tau*DDIM + tid];
        const float* wp = wi3 + (size_t)tau*HDIM*DDIM + tid;
        for (int d = 0; d < HDIM; d++) a += ys[tau][d]*wp[d*DDIM];
        di += a;
    }
    float hv = hin[(size_t)s*DDIM + tid];
    float v0 = hv + dself[(size_t)s*DDIM + tid];
    float v1 = di;
    __syncthreads();
    float sum = blockReduce128(v0 + v1, red);
    float mu = sum * (1.0f/(2*DDIM));
    float d0 = v0 - mu, d1 = v1 - mu;
    float var = blockReduce128(d0*d0 + d1*d1, red) * (1.0f/(2*DDIM));
    float rs = rsqrtf(var + EPSLN);
    comb[tid]        = d0*rs*lu_g[tid] + lu_b[tid];
    comb[DDIM + tid] = d1*rs*lu_g[DDIM + tid] + lu_b[DDIM + tid];
    __syncthreads();
    float a1 = bu1[tid];
    for (int d = 0; d < 2*DDIM; d++) a1 += comb[d]*wu1[d*HDIM + tid];
    u1[tid] = fmaxf(a1, 0.f);
    __syncthreads();
    float a2 = bu2[tid];
    for (int d = 0; d < HDIM; d++) a2 += u1[d]*wu2[d*DDIM + tid];
    hout[(size_t)s*DDIM + tid] = hv + a2;
}

// ---------- launch ----------
extern "C" void kernel_launch(void* const* d_in, const int* in_sizes, int n_in,
                              void* d_out, int out_size, void* d_ws, size_t ws_size,
                              hipStream_t stream) {
    const float* slots = (const float*)d_in[0];
    const float* ep    = (const float*)d_in[1];
    const float* et    = (const float*)d_in[2];
    const float* ls_g  = (const float*)d_in[3];
    const float* ls_b  = (const float*)d_in[4];
    const float* ws1   = (const float*)d_in[5];
    const float* bs1   = (const float*)d_in[6];
    const float* ws2   = (const float*)d_in[7];
    const float* bs2   = (const float*)d_in[8];
    const float* wi1   = (const float*)d_in[9];
    const float* bi1   = (const float*)d_in[10];
    const float* wi2   = (const float*)d_in[11];
    const float* bi2   = (const float*)d_in[12];
    const float* wi3   = (const float*)d_in[13];
    const float* bi3   = (const float*)d_in[14];
    const float* lu_g  = (const float*)d_in[15];
    const float* lu_b  = (const float*)d_in[16];
    const float* wu1   = (const float*)d_in[17];
    const float* bu1   = (const float*)d_in[18];
    const float* wu2   = (const float*)d_in[19];
    const float* bu2   = (const float*)d_in[20];
    float* out = (float*)d_out;

    char* wsb = (char*)d_ws;
    float* h_buf = (float*)wsb;                 wsb += (size_t)NSLOT*DDIM*4;
    float* dself = (float*)wsb;                 wsb += (size_t)NSLOT*DDIM*4;
    __half* At   = (__half*)wsb;                wsb += (size_t)TTYPE*NSLOT*HDIM*2;
    __half* Ct   = (__half*)wsb;                wsb += (size_t)TTYPE*NSLOT*HDIM*2;
    float* yb    = (float*)wsb;                 wsb += (size_t)TTYPE*NSLOT*HDIM*4;
    float* wsumb = (float*)wsb;                 wsb += (size_t)TTYPE*NSLOT*4;

    for (int mp = 0; mp < 2; mp++) {
        const float* hin = (mp == 0) ? slots : h_buf;
        float* hout = (mp == 0) ? h_buf : out;
        k_self<<<NSLOT, 128, 0, stream>>>(hin, ls_g, ls_b, ws1, bs1, ws2, bs2, dself);
        k_proj<<<NSLOT/8, 256, 0, stream>>>(hin, wi1, bi1, At, Ct);
        k_pair<<<BATCH*TTYPE, 256, 0, stream>>>(At, Ct, wi2, bi2, ep, et, yb, wsumb);
        k_update<<<NSLOT, 128, 0, stream>>>(hin, dself, yb, wsumb, wi3, bi3,
                                            lu_g, lu_b, wu1, bu1, wu2, bu2, hout);
    }
}

// Round 3
// 384.752 us; speedup vs baseline: 3.2452x; 1.0417x over previous
//
#include <hip/hip_runtime.h>
#include <hip/hip_fp16.h>

#define BATCH 64
#define KSLOT 64
#define DDIM  128
#define HDIM  128
#define TTYPE 4
#define NSLOT (BATCH*KSLOT)
#define EPSLN 1e-5f
#define YROW  544   // 4*128 y + 4 wsum + 28 zero pad

typedef _Float16 v8h __attribute__((ext_vector_type(8)));
typedef float    v4f __attribute__((ext_vector_type(4)));

__device__ __forceinline__ float waveAllSum(float v) {
    #pragma unroll
    for (int m = 1; m < 64; m <<= 1) v += __shfl_xor(v, m, 64);
    return v;
}

// ---------- k_wconv: one-time weight transpose/convert to f16 [n][k] ----------
__global__ __launch_bounds__(256) void k_wconv(
        const float* __restrict__ ws1, const float* __restrict__ wi1,
        const float* __restrict__ ws2, const float* __restrict__ wu1,
        const float* __restrict__ wu2, const float* __restrict__ wi3,
        const float* __restrict__ wi2, const float* __restrict__ bi1,
        const float* __restrict__ bi3,
        __half* __restrict__ ws1T, __half* __restrict__ wi1catT,
        __half* __restrict__ ws2T, __half* __restrict__ wu1T,
        __half* __restrict__ wu2T, __half* __restrict__ w3catT,
        __half* __restrict__ w2T16, float* __restrict__ biascat) {
    __shared__ __align__(16) float tile[128*132];
    int bx = blockIdx.x, tid = threadIdx.x;
    if (bx == 21) {
        // w3catT pad cols 512..543 (bi3 rows then zeros) + biascat
        for (int idx = tid; idx < 128*32; idx += 256) {
            int o = idx >> 5, c = idx & 31;
            w3catT[(size_t)o*YROW + 512 + c] = (c < 4) ? __float2half(bi3[c*DDIM + o]) : __float2half(0.f);
        }
        for (int idx = tid; idx < 1024; idx += 256) {
            int th = idx >> 7, o = idx & 127;
            biascat[idx] = (th & 1) ? bi1[(th>>1)*HDIM + o] : 0.f;
        }
        return;
    }
    const float* src; __half* dst; int dstride = 128, dcol = 0;
    if (bx == 0)      { src = ws1; dst = ws1T; }
    else if (bx <= 8) { int th = bx-1, tau = th>>1, half = th&1;
                        src = wi1 + ((size_t)tau*256 + half*128)*128;
                        dst = wi1catT + (size_t)th*128*128; }
    else if (bx == 9) { src = ws2; dst = ws2T; }
    else if (bx ==10) { src = wu2; dst = wu2T; }
    else if (bx <=12) { int hh = bx-11; src = wu1 + (size_t)hh*128*128;
                        dst = wu1T; dstride = 256; dcol = hh*128; }
    else if (bx <=16) { int tau = bx-13; src = wi3 + (size_t)tau*16384;
                        dst = w3catT; dstride = YROW; dcol = tau*128; }
    else              { int tau = bx-17; src = wi2 + (size_t)tau*16384;
                        dst = w2T16 + (size_t)tau*16384; }
    for (int idx = tid; idx < 4096; idx += 256) {        // float4 units
        int r = idx >> 5, c4 = idx & 31;
        *(float4*)&tile[r*132 + c4*4] = *(const float4*)&src[(size_t)r*128 + c4*4];
    }
    __syncthreads();
    for (int idx = tid; idx < 8192; idx += 256) {        // half2 units of dst
        int n = idx >> 6, kp = idx & 63;
        __half2 p = __floats2half2_rn(tile[(2*kp)*132 + n], tile[(2*kp+1)*132 + n]);
        *(__half2*)&dst[(size_t)n*dstride + dcol + 2*kp] = p;
    }
}

// ---------- k_ln1: wave-per-slot LN(128) -> hn16, plus h16 cast; zero Ycat pad ----------
__global__ __launch_bounds__(256) void k_ln1(
        const float* __restrict__ h, const float* __restrict__ g, const float* __restrict__ bb,
        __half* __restrict__ h16, __half* __restrict__ hn16, __half* __restrict__ Ycat) {
    int s = blockIdx.x*4 + (threadIdx.x >> 6);
    int L = threadIdx.x & 63;
    float2 hv = *(const float2*)&h[(size_t)s*DDIM + L*2];
    float mu = waveAllSum(hv.x + hv.y) * (1.0f/DDIM);
    float dx = hv.x - mu, dy = hv.y - mu;
    float var = waveAllSum(dx*dx + dy*dy) * (1.0f/DDIM);
    float rs = rsqrtf(var + EPSLN);
    float2 gv = *(const float2*)&g[L*2];
    float2 bv = *(const float2*)&bb[L*2];
    *(__half2*)&h16[(size_t)s*DDIM + L*2]  = __floats2half2_rn(hv.x, hv.y);
    *(__half2*)&hn16[(size_t)s*DDIM + L*2] = __floats2half2_rn(dx*rs*gv.x + bv.x, dy*rs*gv.y + bv.y);
    if (L < 28) Ycat[(size_t)s*YROW + 516 + L] = __float2half(0.f);
}

// ---------- k_ln2: wave-per-slot LN(256) over comb -> cln16 ----------
__global__ __launch_bounds__(256) void k_ln2(
        const float* __restrict__ comb, const float* __restrict__ g, const float* __restrict__ bb,
        __half* __restrict__ cln16) {
    int s = blockIdx.x*4 + (threadIdx.x >> 6);
    int L = threadIdx.x & 63;
    float4 v = *(const float4*)&comb[(size_t)s*256 + L*4];
    float mu = waveAllSum(v.x + v.y + v.z + v.w) * (1.0f/256.f);
    float d0 = v.x-mu, d1 = v.y-mu, d2 = v.z-mu, d3 = v.w-mu;
    float var = waveAllSum(d0*d0 + d1*d1 + d2*d2 + d3*d3) * (1.0f/256.f);
    float rs = rsqrtf(var + EPSLN);
    float4 gv = *(const float4*)&g[L*4];
    float4 bv = *(const float4*)&bb[L*4];
    *(__half2*)&cln16[(size_t)s*256 + L*4]     = __floats2half2_rn(d0*rs*gv.x + bv.x, d1*rs*gv.y + bv.y);
    *(__half2*)&cln16[(size_t)s*256 + L*4 + 2] = __floats2half2_rn(d2*rs*gv.z + bv.z, d3*rs*gv.w + bv.w);
}

// ---------- k_gemm: generic f16 MFMA GEMM, M=4096, BT = [N][K] f16 ----------
// BM=32 (2 waves x 16 rows), BN=128 (8 o-tiles), BK=32.
__global__ __launch_bounds__(128) void k_gemm(
        const __half* __restrict__ A,    // [4096][K]
        const __half* __restrict__ BT,   // [N][K]
        const float* __restrict__ bias,  // [N] or null
        const float* __restrict__ resid, // [4096][128] fp32 or null (N==128 only)
        float* __restrict__ outf,        // fp32 out or null
        __half* __restrict__ outh,       // f16 out or null
        int K, int ostride, int ocol, int do_relu) {
    __shared__ __align__(16) _Float16 Asm[32*40];
    __shared__ __align__(16) _Float16 Bsm[128*40];
    int tid = threadIdx.x, lane = tid & 63, w = tid >> 6;
    int n = lane & 15, quad = lane >> 4;
    int mb = blockIdx.x, nb = blockIdx.y;
    const __half* Ab = A  + (size_t)mb*32*K;
    const __half* Bb = BT + (size_t)nb*128*K;
    v4f acc[8];
    #pragma unroll
    for (int ot = 0; ot < 8; ot++) {
        float b0 = bias ? bias[nb*128 + ot*16 + n] : 0.f;
        acc[ot] = (v4f){b0, b0, b0, b0};
    }
    int arow = tid >> 2, aseg = (tid & 3)*8;
    for (int kk = 0; kk < K; kk += 32) {
        *(v8h*)&Asm[arow*40 + aseg] = *(const v8h*)&Ab[(size_t)arow*K + kk + aseg];
        #pragma unroll
        for (int ii = 0; ii < 4; ii++)
            *(v8h*)&Bsm[(ii*32 + arow)*40 + aseg] = *(const v8h*)&Bb[(size_t)(ii*32 + arow)*K + kk + aseg];
        __syncthreads();
        v8h a = *(const v8h*)&Asm[(w*16 + n)*40 + quad*8];
        #pragma unroll
        for (int ot = 0; ot < 8; ot++)
            acc[ot] = __builtin_amdgcn_mfma_f32_16x16x32_f16(
                a, *(const v8h*)&Bsm[(ot*16 + n)*40 + quad*8], acc[ot], 0, 0, 0);
        __syncthreads();
    }
    #pragma unroll
    for (int ot = 0; ot < 8; ot++) {
        #pragma unroll
        for (int r = 0; r < 4; r++) {
            int row = mb*32 + w*16 + quad*4 + r;
            int gcol = nb*128 + ot*16 + n;
            float v = acc[ot][r];
            if (do_relu) v = fmaxf(v, 0.f);
            if (resid) v += resid[(size_t)row*128 + gcol];
            if (outf) outf[(size_t)row*ostride + ocol + gcol] = v;
            else      outh[(size_t)row*ostride + ocol + gcol] = __float2half(v);
        }
    }
}

// ---------- k_pair: MFMA pair kernel (2 blocks/CU) ----------
#define LROW 136
__global__ __launch_bounds__(256, 2) void k_pair(
        const __half* __restrict__ AtCt,   // [4096][1024]: cols th*128+o, th=tau*2+half
        const __half* __restrict__ w2T16,  // [4][128][128] = wi2^T f16
        const float* __restrict__ bi2,
        const float* __restrict__ ep, const float* __restrict__ et,
        __half* __restrict__ Ycat) {       // [4096][YROW]
    __shared__ __align__(16) _Float16 w2T[HDIM*LROW];   // 34816 B
    __shared__ __align__(16) _Float16 Cs[KSLOT*LROW];   // 17408 B
    __shared__ __align__(16) _Float16 As[KSLOT*LROW];   // 17408 B
    __shared__ __align__(16) _Float16 wS[KSLOT*KSLOT];  //  8192 B  -> total 77824 B

    int bx = blockIdx.x;
    int b = bx >> 2, tau = bx & 3;
    int tid = threadIdx.x;
    int lane = tid & 63, jt = tid >> 6, quad = lane >> 4, n = lane & 15;

    for (int idx = tid; idx < 2048; idx += 256) {       // stage wi2^T
        int o = idx >> 4, seg = (idx & 15)*8;
        *(v8h*)&w2T[o*LROW + seg] = *(const v8h*)&w2T16[((size_t)tau*128 + o)*128 + seg];
    }
    for (int u = tid; u < KSLOT*16; u += 256) {         // stage A,C rows
        int j = u >> 4, seg = (u & 15)*8;
        const __half* rp = AtCt + (size_t)(b*KSLOT + j)*1024 + tau*256 + seg;
        *(v8h*)&As[j*LROW + seg] = *(const v8h*)&rp[0];
        *(v8h*)&Cs[j*LROW + seg] = *(const v8h*)&rp[128];
    }
    {
        const float* epb = ep + (size_t)b*KSLOT*KSLOT;
        const float* etb = et + (size_t)b*KSLOT*KSLOT*TTYPE + tau;
        for (int idx = tid; idx < KSLOT*KSLOT; idx += 256)
            wS[idx] = (_Float16)(epb[idx] * etb[(size_t)idx*TTYPE]);
    }
    __syncthreads();

    v8h bfrag[8][4];
    #pragma unroll
    for (int ot = 0; ot < 8; ot++)
        #pragma unroll
        for (int ks = 0; ks < 4; ks++)
            bfrag[ot][ks] = *(const v8h*)&w2T[(ot*16 + n)*LROW + ks*32 + quad*8];
    v8h cfrag[4];
    #pragma unroll
    for (int ks = 0; ks < 4; ks++)
        cfrag[ks] = *(const v8h*)&Cs[(jt*16 + n)*LROW + ks*32 + quad*8];
    float biasv[8];
    #pragma unroll
    for (int ot = 0; ot < 8; ot++) biasv[ot] = bi2[tau*HDIM + ot*16 + n];

    v4f yacc[8];
    #pragma unroll
    for (int ot = 0; ot < 8; ot++) yacc[ot] = (v4f){0.f,0.f,0.f,0.f};
    float wsacc[4] = {0.f,0.f,0.f,0.f};
    const v8h zero8 = {0,0,0,0,0,0,0,0};

    for (int i = 0; i < KSLOT; ++i) {
        v8h a[4];
        #pragma unroll
        for (int ks = 0; ks < 4; ks++)
            a[ks] = *(const v8h*)&As[i*LROW + ks*32 + quad*8];
        float wv[4];
        #pragma unroll
        for (int r = 0; r < 4; r++)
            wv[r] = (float)wS[i*KSLOT + jt*16 + quad*4 + r];
        v8h x1[4];
        #pragma unroll
        for (int ks = 0; ks < 4; ks++)
            x1[ks] = __builtin_elementwise_max(a[ks] + cfrag[ks], zero8);
        #pragma unroll
        for (int ot = 0; ot < 8; ot++) {
            v4f acc = (v4f){biasv[ot], biasv[ot], biasv[ot], biasv[ot]};
            #pragma unroll
            for (int ks = 0; ks < 4; ks++)
                acc = __builtin_amdgcn_mfma_f32_16x16x32_f16(x1[ks], bfrag[ot][ks], acc, 0, 0, 0);
            #pragma unroll
            for (int r = 0; r < 4; r++)
                yacc[ot][r] = fmaf(wv[r], fmaxf(acc[r], 0.f), yacc[ot][r]);
        }
        #pragma unroll
        for (int r = 0; r < 4; r++) wsacc[r] += wv[r];
    }

    #pragma unroll
    for (int r = 0; r < 4; r++) {
        int j = jt*16 + quad*4 + r;
        __half* yb = Ycat + (size_t)(b*KSLOT + j)*YROW + tau*128;
        #pragma unroll
        for (int ot = 0; ot < 8; ot++)
            yb[ot*16 + n] = __float2half(yacc[ot][r]);
    }
    if (n == 0) {
        #pragma unroll
        for (int r = 0; r < 4; r++)
            Ycat[(size_t)(b*KSLOT + jt*16 + quad*4 + r)*YROW + 512 + tau] = __float2half(wsacc[r]);
    }
}

// ---------- launch ----------
extern "C" void kernel_launch(void* const* d_in, const int* in_sizes, int n_in,
                              void* d_out, int out_size, void* d_ws, size_t ws_size,
                              hipStream_t stream) {
    const float* slots = (const float*)d_in[0];
    const float* ep    = (const float*)d_in[1];
    const float* et    = (const float*)d_in[2];
    const float* ls_g  = (const float*)d_in[3];
    const float* ls_b  = (const float*)d_in[4];
    const float* ws1   = (const float*)d_in[5];
    const float* bs1   = (const float*)d_in[6];
    const float* ws2   = (const float*)d_in[7];
    const float* bs2   = (const float*)d_in[8];
    const float* wi1   = (const float*)d_in[9];
    const float* bi1   = (const float*)d_in[10];
    const float* wi2   = (const float*)d_in[11];
    const float* bi2   = (const float*)d_in[12];
    const float* wi3   = (const float*)d_in[13];
    const float* bi3   = (const float*)d_in[14];
    const float* lu_g  = (const float*)d_in[15];
    const float* lu_b  = (const float*)d_in[16];
    const float* wu1   = (const float*)d_in[17];
    const float* bu1   = (const float*)d_in[18];
    const float* wu2   = (const float*)d_in[19];
    const float* bu2   = (const float*)d_in[20];
    float* out = (float*)d_out;

    char* p = (char*)d_ws;
    float*  h_buf   = (float*)p;   p += (size_t)NSLOT*DDIM*4;
    __half* h16     = (__half*)p;  p += (size_t)NSLOT*DDIM*2;
    __half* hn16    = (__half*)p;  p += (size_t)NSLOT*DDIM*2;
    __half* t1      = (__half*)p;  p += (size_t)NSLOT*HDIM*2;
    __half* AtCt    = (__half*)p;  p += (size_t)NSLOT*1024*2;
    __half* Ycat    = (__half*)p;  p += (size_t)NSLOT*YROW*2;
    float*  comb    = (float*)p;   p += (size_t)NSLOT*256*4;
    __half* cln16   = (__half*)p;  p += (size_t)NSLOT*256*2;
    __half* u16     = (__half*)p;  p += (size_t)NSLOT*HDIM*2;
    __half* ws1T    = (__half*)p;  p += 128*128*2;
    __half* wi1catT = (__half*)p;  p += 1024*128*2;
    __half* ws2T    = (__half*)p;  p += 128*128*2;
    __half* wu1T    = (__half*)p;  p += 128*256*2;
    __half* wu2T    = (__half*)p;  p += 128*128*2;
    __half* w3catT  = (__half*)p;  p += 128*YROW*2;
    __half* w2T16   = (__half*)p;  p += 4*128*128*2;
    float*  biascat = (float*)p;   p += 1024*4;

    k_wconv<<<22, 256, 0, stream>>>(ws1, wi1, ws2, wu1, wu2, wi3, wi2, bi1, bi3,
                                    ws1T, wi1catT, ws2T, wu1T, wu2T, w3catT, w2T16, biascat);

    for (int mp = 0; mp < 2; mp++) {
        const float* h = (mp == 0) ? slots : h_buf;
        float* hout = (mp == 0) ? h_buf : out;
        k_ln1<<<NSLOT/4, 256, 0, stream>>>(h, ls_g, ls_b, h16, hn16, Ycat);
        // t1 = relu(hn @ ws1 + bs1)
        k_gemm<<<dim3(128,1), 128, 0, stream>>>(hn16, ws1T, bs1, nullptr,
                                                nullptr, t1, 128, 128, 0, 1);
        // AtCt = h @ wi1cat (+bi1 on C halves)
        k_gemm<<<dim3(128,8), 128, 0, stream>>>(h16, wi1catT, biascat, nullptr,
                                                nullptr, AtCt, 128, 1024, 0, 0);
        k_pair<<<BATCH*TTYPE, 256, 0, stream>>>(AtCt, w2T16, bi2, ep, et, Ycat);
        // comb[:,0:128] = h + t1 @ ws2 + bs2
        k_gemm<<<dim3(128,1), 128, 0, stream>>>(t1, ws2T, bs2, h,
                                                comb, nullptr, 128, 256, 0, 0);
        // comb[:,128:256] = Ycat @ w3cat  (includes wsum*bi3 via extended K)
        k_gemm<<<dim3(128,1), 128, 0, stream>>>(Ycat, w3catT, nullptr, nullptr,
                                                comb, nullptr, YROW, 256, 128, 0);
        k_ln2<<<NSLOT/4, 256, 0, stream>>>(comb, lu_g, lu_b, cln16);
        // u = relu(cln @ wu1 + bu1)
        k_gemm<<<dim3(128,1), 128, 0, stream>>>(cln16, wu1T, bu1, nullptr,
                                                nullptr, u16, 256, 128, 0, 1);
        // hout = h + u @ wu2 + bu2
        k_gemm<<<dim3(128,1), 128, 0, stream>>>(u16, wu2T, bu2, h,
                                                hout, nullptr, 128, 128, 0, 0);
    }
}

// Round 4
// 253.120 us; speedup vs baseline: 4.9329x; 1.5200x over previous
//
#include <hip/hip_runtime.h>
#include <hip/hip_fp16.h>

#define BATCH 64
#define KSLOT 64
#define DDIM  128
#define HDIM  128
#define TTYPE 4
#define NSLOT (BATCH*KSLOT)
#define EPSLN 1e-5f
#define YROW  544   // 4*128 y + 4 wsum + 28 pad (pad killed by zero weight cols)

typedef _Float16 v8h __attribute__((ext_vector_type(8)));
typedef _Float16 v4h __attribute__((ext_vector_type(4)));
typedef float    v4f __attribute__((ext_vector_type(4)));

__device__ __forceinline__ float waveAllSum(float v) {
    #pragma unroll
    for (int m = 1; m < 64; m <<= 1) v += __shfl_xor(v, m, 64);
    return v;
}

// ---------- k_wconv: one-time weight transpose/convert to f16 [n][k] ----------
__global__ __launch_bounds__(256) void k_wconv(
        const float* __restrict__ ws1, const float* __restrict__ wi1,
        const float* __restrict__ ws2, const float* __restrict__ wu1,
        const float* __restrict__ wu2, const float* __restrict__ wi3,
        const float* __restrict__ wi2, const float* __restrict__ bi1,
        const float* __restrict__ bi3,
        __half* __restrict__ ws1T, __half* __restrict__ wi1catT,
        __half* __restrict__ ws2T, __half* __restrict__ wu1T,
        __half* __restrict__ wu2T, __half* __restrict__ w3catT,
        __half* __restrict__ w2T16, float* __restrict__ biascat) {
    __shared__ __align__(16) float tile[128*132];
    int bx = blockIdx.x, tid = threadIdx.x;
    if (bx == 21) {
        for (int idx = tid; idx < 128*32; idx += 256) {
            int o = idx >> 5, c = idx & 31;
            w3catT[(size_t)o*YROW + 512 + c] = (c < 4) ? __float2half(bi3[c*DDIM + o]) : __float2half(0.f);
        }
        for (int idx = tid; idx < 1024; idx += 256) {
            int th = idx >> 7, o = idx & 127;
            biascat[idx] = (th & 1) ? bi1[(th>>1)*HDIM + o] : 0.f;
        }
        return;
    }
    const float* src; __half* dst; int dstride = 128, dcol = 0;
    if (bx == 0)      { src = ws1; dst = ws1T; }
    else if (bx <= 8) { int th = bx-1, tau = th>>1, half = th&1;
                        src = wi1 + ((size_t)tau*256 + half*128)*128;
                        dst = wi1catT + (size_t)th*128*128; }
    else if (bx == 9) { src = ws2; dst = ws2T; }
    else if (bx ==10) { src = wu2; dst = wu2T; }
    else if (bx <=12) { int hh = bx-11; src = wu1 + (size_t)hh*128*128;
                        dst = wu1T; dstride = 256; dcol = hh*128; }
    else if (bx <=16) { int tau = bx-13; src = wi3 + (size_t)tau*16384;
                        dst = w3catT; dstride = YROW; dcol = tau*128; }
    else              { int tau = bx-17; src = wi2 + (size_t)tau*16384;
                        dst = w2T16 + (size_t)tau*16384; }
    for (int idx = tid; idx < 4096; idx += 256) {
        int r = idx >> 5, c4 = idx & 31;
        *(float4*)&tile[r*132 + c4*4] = *(const float4*)&src[(size_t)r*128 + c4*4];
    }
    __syncthreads();
    for (int idx = tid; idx < 8192; idx += 256) {
        int n = idx >> 6, kp = idx & 63;
        __half2 p = __floats2half2_rn(tile[(2*kp)*132 + n], tile[(2*kp+1)*132 + n]);
        *(__half2*)&dst[(size_t)n*dstride + dcol + 2*kp] = p;
    }
}

// ---------- k_gemm32: AtCt = cast_f16(h) @ wi1cat + biascat ----------
__global__ __launch_bounds__(128) void k_gemm32(
        const float* __restrict__ A,     // [4096][K] fp32
        const __half* __restrict__ BT,   // [N][K] f16
        const float* __restrict__ bias,
        __half* __restrict__ outh, int K, int ostride) {
    __shared__ __align__(16) _Float16 Asm[32*40];
    __shared__ __align__(16) _Float16 Bsm[128*40];
    int tid = threadIdx.x, lane = tid & 63, w = tid >> 6;
    int n = lane & 15, quad = lane >> 4;
    int mb = blockIdx.x, nb = blockIdx.y;
    const float* Ab = A + (size_t)mb*32*K;
    const __half* Bb = BT + (size_t)nb*128*K;
    v4f acc[8];
    #pragma unroll
    for (int ot = 0; ot < 8; ot++) {
        float b0 = bias ? bias[nb*128 + ot*16 + n] : 0.f;
        acc[ot] = (v4f){b0, b0, b0, b0};
    }
    int arow = tid >> 2, aseg = (tid & 3)*8;
    for (int kk = 0; kk < K; kk += 32) {
        float4 f0 = *(const float4*)&Ab[(size_t)arow*K + kk + aseg];
        float4 f1 = *(const float4*)&Ab[(size_t)arow*K + kk + aseg + 4];
        *(__half2*)&Asm[arow*40 + aseg]     = __floats2half2_rn(f0.x, f0.y);
        *(__half2*)&Asm[arow*40 + aseg + 2] = __floats2half2_rn(f0.z, f0.w);
        *(__half2*)&Asm[arow*40 + aseg + 4] = __floats2half2_rn(f1.x, f1.y);
        *(__half2*)&Asm[arow*40 + aseg + 6] = __floats2half2_rn(f1.z, f1.w);
        #pragma unroll
        for (int ii = 0; ii < 4; ii++)
            *(v8h*)&Bsm[(ii*32 + arow)*40 + aseg] = *(const v8h*)&Bb[(size_t)(ii*32 + arow)*K + kk + aseg];
        __syncthreads();
        v8h a = *(const v8h*)&Asm[(w*16 + n)*40 + quad*8];
        #pragma unroll
        for (int ot = 0; ot < 8; ot++)
            acc[ot] = __builtin_amdgcn_mfma_f32_16x16x32_f16(
                a, *(const v8h*)&Bsm[(ot*16 + n)*40 + quad*8], acc[ot], 0, 0, 0);
        __syncthreads();
    }
    #pragma unroll
    for (int ot = 0; ot < 8; ot++)
        #pragma unroll
        for (int r = 0; r < 4; r++) {
            int row = mb*32 + w*16 + quad*4 + r, col = nb*128 + ot*16 + n;
            outh[(size_t)row*ostride + col] = __float2half(acc[ot][r]);
        }
}

// ---------- k_gemm16: comb[:,128:256] = Ycat @ w3catT (K=544) ----------
__global__ __launch_bounds__(128) void k_gemm16(
        const __half* __restrict__ A, const __half* __restrict__ BT,
        float* __restrict__ outf, int K, int ostride, int ocol) {
    __shared__ __align__(16) _Float16 Asm[32*40];
    __shared__ __align__(16) _Float16 Bsm[128*40];
    int tid = threadIdx.x, lane = tid & 63, w = tid >> 6;
    int n = lane & 15, quad = lane >> 4;
    int mb = blockIdx.x;
    const __half* Ab = A + (size_t)mb*32*K;
    const __half* Bb = BT;
    v4f acc[8];
    #pragma unroll
    for (int ot = 0; ot < 8; ot++) acc[ot] = (v4f){0.f,0.f,0.f,0.f};
    int arow = tid >> 2, aseg = (tid & 3)*8;
    for (int kk = 0; kk < K; kk += 32) {
        *(v8h*)&Asm[arow*40 + aseg] = *(const v8h*)&Ab[(size_t)arow*K + kk + aseg];
        #pragma unroll
        for (int ii = 0; ii < 4; ii++)
            *(v8h*)&Bsm[(ii*32 + arow)*40 + aseg] = *(const v8h*)&Bb[(size_t)(ii*32 + arow)*K + kk + aseg];
        __syncthreads();
        v8h a = *(const v8h*)&Asm[(w*16 + n)*40 + quad*8];
        #pragma unroll
        for (int ot = 0; ot < 8; ot++)
            acc[ot] = __builtin_amdgcn_mfma_f32_16x16x32_f16(
                a, *(const v8h*)&Bsm[(ot*16 + n)*40 + quad*8], acc[ot], 0, 0, 0);
        __syncthreads();
    }
    #pragma unroll
    for (int ot = 0; ot < 8; ot++)
        #pragma unroll
        for (int r = 0; r < 4; r++) {
            int row = mb*32 + w*16 + quad*4 + r, col = ot*16 + n;
            outf[(size_t)row*ostride + ocol + col] = acc[ot][r];
        }
}

// ---------- k_fused_self: LN + MLP(f_self) + residual -> comb[:,0:128] ----------
__global__ __launch_bounds__(256) void k_fused_self(
        const float* __restrict__ h, const float* __restrict__ g, const float* __restrict__ bb,
        const __half* __restrict__ ws1T, const float* __restrict__ bs1,
        const __half* __restrict__ ws2T, const float* __restrict__ bs2,
        float* __restrict__ comb) {
    __shared__ __align__(16) _Float16 W1[128*136];
    __shared__ __align__(16) _Float16 W2[128*136];
    __shared__ __align__(16) float    Hrow[16*132];
    __shared__ __align__(16) _Float16 Xa[16*136];
    __shared__ __align__(16) _Float16 Tt[16*136];
    int tid = threadIdx.x, lane = tid & 63, w = tid >> 6;
    int n = lane & 15, quad = lane >> 4;
    int row0 = blockIdx.x*16;
    for (int idx = tid; idx < 128*16; idx += 256) {
        int r = idx >> 4, s = (idx & 15)*8;
        *(v8h*)&W1[r*136 + s] = *(const v8h*)&ws1T[r*128 + s];
        *(v8h*)&W2[r*136 + s] = *(const v8h*)&ws2T[r*128 + s];
    }
    for (int idx = tid; idx < 16*32; idx += 256) {
        int r = idx >> 5, c4 = (idx & 31)*4;
        *(float4*)&Hrow[r*132 + c4] = *(const float4*)&h[(size_t)(row0 + r)*128 + c4];
    }
    __syncthreads();
    #pragma unroll
    for (int rr = 0; rr < 4; rr++) {
        int r = w*4 + rr;
        float x0 = Hrow[r*132 + 2*lane], x1 = Hrow[r*132 + 2*lane + 1];
        float mu = waveAllSum(x0 + x1) * (1.f/128.f);
        float d0 = x0 - mu, d1 = x1 - mu;
        float var = waveAllSum(d0*d0 + d1*d1) * (1.f/128.f);
        float rs = rsqrtf(var + EPSLN);
        float2 gv = *(const float2*)&g[2*lane];
        float2 bv = *(const float2*)&bb[2*lane];
        *(__half2*)&Xa[r*136 + 2*lane] = __floats2half2_rn(d0*rs*gv.x + bv.x, d1*rs*gv.y + bv.y);
    }
    __syncthreads();
    v4f acc[2];
    #pragma unroll
    for (int ot = 0; ot < 2; ot++) { float b0 = bs1[w*32 + ot*16 + n]; acc[ot] = (v4f){b0,b0,b0,b0}; }
    #pragma unroll
    for (int ks = 0; ks < 4; ks++) {
        v8h a = *(const v8h*)&Xa[n*136 + ks*32 + quad*8];
        #pragma unroll
        for (int ot = 0; ot < 2; ot++)
            acc[ot] = __builtin_amdgcn_mfma_f32_16x16x32_f16(
                a, *(const v8h*)&W1[(w*32 + ot*16 + n)*136 + ks*32 + quad*8], acc[ot], 0, 0, 0);
    }
    #pragma unroll
    for (int ot = 0; ot < 2; ot++)
        #pragma unroll
        for (int r = 0; r < 4; r++)
            Tt[(quad*4 + r)*136 + w*32 + ot*16 + n] = (_Float16)fmaxf(acc[ot][r], 0.f);
    __syncthreads();
    #pragma unroll
    for (int ot = 0; ot < 2; ot++) { float b0 = bs2[w*32 + ot*16 + n]; acc[ot] = (v4f){b0,b0,b0,b0}; }
    #pragma unroll
    for (int ks = 0; ks < 4; ks++) {
        v8h a = *(const v8h*)&Tt[n*136 + ks*32 + quad*8];
        #pragma unroll
        for (int ot = 0; ot < 2; ot++)
            acc[ot] = __builtin_amdgcn_mfma_f32_16x16x32_f16(
                a, *(const v8h*)&W2[(w*32 + ot*16 + n)*136 + ks*32 + quad*8], acc[ot], 0, 0, 0);
    }
    #pragma unroll
    for (int ot = 0; ot < 2; ot++)
        #pragma unroll
        for (int r = 0; r < 4; r++) {
            int rr = quad*4 + r, col = w*32 + ot*16 + n;
            comb[(size_t)(row0 + rr)*256 + col] = Hrow[rr*132 + col] + acc[ot][r];
        }
}

// ---------- k_fused_update: LN(256) + MLP(update) + residual -> hout ----------
__global__ __launch_bounds__(256) void k_fused_update(
        const float* __restrict__ comb, const float* __restrict__ g, const float* __restrict__ bb,
        const __half* __restrict__ wu1T, const float* __restrict__ bu1,
        const __half* __restrict__ wu2T, const float* __restrict__ bu2,
        const float* __restrict__ h, float* __restrict__ hout) {
    __shared__ __align__(16) _Float16 W1[128*264];
    __shared__ __align__(16) _Float16 W2[128*136];
    __shared__ __align__(16) float    Crow[16*260];
    __shared__ __align__(16) _Float16 Xa[16*264];
    __shared__ __align__(16) _Float16 Ut[16*136];
    int tid = threadIdx.x, lane = tid & 63, w = tid >> 6;
    int n = lane & 15, quad = lane >> 4;
    int row0 = blockIdx.x*16;
    for (int idx = tid; idx < 128*32; idx += 256) {
        int r = idx >> 5, s = (idx & 31)*8;
        *(v8h*)&W1[r*264 + s] = *(const v8h*)&wu1T[(size_t)r*256 + s];
    }
    for (int idx = tid; idx < 128*16; idx += 256) {
        int r = idx >> 4, s = (idx & 15)*8;
        *(v8h*)&W2[r*136 + s] = *(const v8h*)&wu2T[r*128 + s];
    }
    for (int idx = tid; idx < 16*64; idx += 256) {
        int r = idx >> 6, c4 = (idx & 63)*4;
        *(float4*)&Crow[r*260 + c4] = *(const float4*)&comb[(size_t)(row0 + r)*256 + c4];
    }
    __syncthreads();
    #pragma unroll
    for (int rr = 0; rr < 4; rr++) {
        int r = w*4 + rr;
        float4 v = *(const float4*)&Crow[r*260 + 4*lane];
        float mu = waveAllSum(v.x + v.y + v.z + v.w) * (1.f/256.f);
        float d0 = v.x-mu, d1 = v.y-mu, d2 = v.z-mu, d3 = v.w-mu;
        float var = waveAllSum(d0*d0 + d1*d1 + d2*d2 + d3*d3) * (1.f/256.f);
        float rs = rsqrtf(var + EPSLN);
        float4 gv = *(const float4*)&g[4*lane];
        float4 bv = *(const float4*)&bb[4*lane];
        *(__half2*)&Xa[r*264 + 4*lane]     = __floats2half2_rn(d0*rs*gv.x + bv.x, d1*rs*gv.y + bv.y);
        *(__half2*)&Xa[r*264 + 4*lane + 2] = __floats2half2_rn(d2*rs*gv.z + bv.z, d3*rs*gv.w + bv.w);
    }
    __syncthreads();
    v4f acc[2];
    #pragma unroll
    for (int ot = 0; ot < 2; ot++) { float b0 = bu1[w*32 + ot*16 + n]; acc[ot] = (v4f){b0,b0,b0,b0}; }
    #pragma unroll
    for (int ks = 0; ks < 8; ks++) {
        v8h a = *(const v8h*)&Xa[n*264 + ks*32 + quad*8];
        #pragma unroll
        for (int ot = 0; ot < 2; ot++)
            acc[ot] = __builtin_amdgcn_mfma_f32_16x16x32_f16(
                a, *(const v8h*)&W1[(w*32 + ot*16 + n)*264 + ks*32 + quad*8], acc[ot], 0, 0, 0);
    }
    #pragma unroll
    for (int ot = 0; ot < 2; ot++)
        #pragma unroll
        for (int r = 0; r < 4; r++)
            Ut[(quad*4 + r)*136 + w*32 + ot*16 + n] = (_Float16)fmaxf(acc[ot][r], 0.f);
    __syncthreads();
    #pragma unroll
    for (int ot = 0; ot < 2; ot++) { float b0 = bu2[w*32 + ot*16 + n]; acc[ot] = (v4f){b0,b0,b0,b0}; }
    #pragma unroll
    for (int ks = 0; ks < 4; ks++) {
        v8h a = *(const v8h*)&Ut[n*136 + ks*32 + quad*8];
        #pragma unroll
        for (int ot = 0; ot < 2; ot++)
            acc[ot] = __builtin_amdgcn_mfma_f32_16x16x32_f16(
                a, *(const v8h*)&W2[(w*32 + ot*16 + n)*136 + ks*32 + quad*8], acc[ot], 0, 0, 0);
    }
    #pragma unroll
    for (int ot = 0; ot < 2; ot++)
        #pragma unroll
        for (int r = 0; r < 4; r++) {
            int rr = quad*4 + r, col = w*32 + ot*16 + n;
            hout[(size_t)(row0 + rr)*128 + col] = h[(size_t)(row0 + rr)*128 + col] + acc[ot][r];
        }
}

// ---------- k_pair: MFMA pair kernel, 8 waves (2/SIMD) ----------
#define LROW 136
__global__ __launch_bounds__(512) void k_pair(
        const __half* __restrict__ AtCt,   // [4096][1024]
        const __half* __restrict__ w2T16,  // [4][128][128]
        const float* __restrict__ bi2,
        const float* __restrict__ ep, const float* __restrict__ et,
        __half* __restrict__ Ycat) {       // [4096][YROW]
    __shared__ __align__(16) _Float16 w2T[HDIM*LROW];
    __shared__ __align__(16) _Float16 Cs[KSLOT*LROW];
    __shared__ __align__(16) _Float16 As[KSLOT*LROW];
    __shared__ __align__(16) _Float16 wS[KSLOT*KSLOT];
    int bx = blockIdx.x, b = bx >> 2, tau = bx & 3;
    int tid = threadIdx.x, lane = tid & 63, w = tid >> 6;
    int jt = w >> 1, oh = w & 1, quad = lane >> 4, n = lane & 15;

    for (int idx = tid; idx < 2048; idx += 512) {
        int o = idx >> 4, seg = (idx & 15)*8;
        *(v8h*)&w2T[o*LROW + seg] = *(const v8h*)&w2T16[((size_t)tau*128 + o)*128 + seg];
    }
    for (int u = tid; u < 1024; u += 512) {
        int j = u >> 4, seg = (u & 15)*8;
        const __half* rp = AtCt + (size_t)(b*KSLOT + j)*1024 + tau*256 + seg;
        *(v8h*)&As[j*LROW + seg] = *(const v8h*)&rp[0];
        *(v8h*)&Cs[j*LROW + seg] = *(const v8h*)&rp[128];
    }
    {
        const float* epb = ep + (size_t)b*KSLOT*KSLOT;
        const float* etb = et + (size_t)b*KSLOT*KSLOT*TTYPE + tau;
        for (int idx = tid; idx < KSLOT*KSLOT; idx += 512)
            wS[idx] = (_Float16)(epb[idx] * etb[(size_t)idx*TTYPE]);
    }
    __syncthreads();

    v8h bfrag[4][4];
    #pragma unroll
    for (int ot = 0; ot < 4; ot++)
        #pragma unroll
        for (int ks = 0; ks < 4; ks++)
            bfrag[ot][ks] = *(const v8h*)&w2T[(oh*64 + ot*16 + n)*LROW + ks*32 + quad*8];
    v8h cfrag[4];
    #pragma unroll
    for (int ks = 0; ks < 4; ks++)
        cfrag[ks] = *(const v8h*)&Cs[(jt*16 + n)*LROW + ks*32 + quad*8];
    float biasv[4];
    #pragma unroll
    for (int ot = 0; ot < 4; ot++) biasv[ot] = bi2[tau*HDIM + oh*64 + ot*16 + n];

    v4f yacc[4];
    #pragma unroll
    for (int ot = 0; ot < 4; ot++) yacc[ot] = (v4f){0.f,0.f,0.f,0.f};
    float wsacc[4] = {0.f,0.f,0.f,0.f};
    const v8h zero8 = {0,0,0,0,0,0,0,0};

    for (int i = 0; i < KSLOT; ++i) {
        v8h x1[4];
        #pragma unroll
        for (int ks = 0; ks < 4; ks++) {
            v8h a = *(const v8h*)&As[i*LROW + ks*32 + quad*8];
            x1[ks] = __builtin_elementwise_max(a + cfrag[ks], zero8);
        }
        v4h wv16 = *(const v4h*)&wS[i*KSLOT + jt*16 + quad*4];
        #pragma unroll
        for (int ot = 0; ot < 4; ot++) {
            v4f acc = (v4f){biasv[ot], biasv[ot], biasv[ot], biasv[ot]};
            #pragma unroll
            for (int ks = 0; ks < 4; ks++)
                acc = __builtin_amdgcn_mfma_f32_16x16x32_f16(x1[ks], bfrag[ot][ks], acc, 0, 0, 0);
            #pragma unroll
            for (int r = 0; r < 4; r++)
                yacc[ot][r] = fmaf((float)wv16[r], fmaxf(acc[r], 0.f), yacc[ot][r]);
        }
        #pragma unroll
        for (int r = 0; r < 4; r++) wsacc[r] += (float)wv16[r];
    }

    #pragma unroll
    for (int r = 0; r < 4; r++) {
        int j = jt*16 + quad*4 + r;
        __half* yb = Ycat + (size_t)(b*KSLOT + j)*YROW + tau*128 + oh*64;
        #pragma unroll
        for (int ot = 0; ot < 4; ot++)
            yb[ot*16 + n] = __float2half(yacc[ot][r]);
    }
    if (oh == 0 && n == 0) {
        #pragma unroll
        for (int r = 0; r < 4; r++)
            Ycat[(size_t)(b*KSLOT + jt*16 + quad*4 + r)*YROW + 512 + tau] = __float2half(wsacc[r]);
    }
}

// ---------- launch ----------
extern "C" void kernel_launch(void* const* d_in, const int* in_sizes, int n_in,
                              void* d_out, int out_size, void* d_ws, size_t ws_size,
                              hipStream_t stream) {
    const float* slots = (const float*)d_in[0];
    const float* ep    = (const float*)d_in[1];
    const float* et    = (const float*)d_in[2];
    const float* ls_g  = (const float*)d_in[3];
    const float* ls_b  = (const float*)d_in[4];
    const float* ws1   = (const float*)d_in[5];
    const float* bs1   = (const float*)d_in[6];
    const float* ws2   = (const float*)d_in[7];
    const float* bs2   = (const float*)d_in[8];
    const float* wi1   = (const float*)d_in[9];
    const float* bi1   = (const float*)d_in[10];
    const float* wi2   = (const float*)d_in[11];
    const float* bi2   = (const float*)d_in[12];
    const float* wi3   = (const float*)d_in[13];
    const float* bi3   = (const float*)d_in[14];
    const float* lu_g  = (const float*)d_in[15];
    const float* lu_b  = (const float*)d_in[16];
    const float* wu1   = (const float*)d_in[17];
    const float* bu1   = (const float*)d_in[18];
    const float* wu2   = (const float*)d_in[19];
    const float* bu2   = (const float*)d_in[20];
    float* out = (float*)d_out;

    char* p = (char*)d_ws;
    float*  h_buf   = (float*)p;   p += (size_t)NSLOT*DDIM*4;
    __half* AtCt    = (__half*)p;  p += (size_t)NSLOT*1024*2;
    __half* Ycat    = (__half*)p;  p += (size_t)NSLOT*YROW*2;
    float*  comb    = (float*)p;   p += (size_t)NSLOT*256*4;
    __half* ws1T    = (__half*)p;  p += 128*128*2;
    __half* wi1catT = (__half*)p;  p += 1024*128*2;
    __half* ws2T    = (__half*)p;  p += 128*128*2;
    __half* wu1T    = (__half*)p;  p += 128*256*2;
    __half* wu2T    = (__half*)p;  p += 128*128*2;
    __half* w3catT  = (__half*)p;  p += 128*YROW*2;
    __half* w2T16   = (__half*)p;  p += 4*128*128*2;
    float*  biascat = (float*)p;   p += 1024*4;

    k_wconv<<<22, 256, 0, stream>>>(ws1, wi1, ws2, wu1, wu2, wi3, wi2, bi1, bi3,
                                    ws1T, wi1catT, ws2T, wu1T, wu2T, w3catT, w2T16, biascat);

    for (int mp = 0; mp < 2; mp++) {
        const float* h = (mp == 0) ? slots : h_buf;
        float* hout = (mp == 0) ? h_buf : out;
        k_gemm32<<<dim3(128, 8), 128, 0, stream>>>(h, wi1catT, biascat, AtCt, 128, 1024);
        k_fused_self<<<NSLOT/16, 256, 0, stream>>>(h, ls_g, ls_b, ws1T, bs1, ws2T, bs2, comb);
        k_pair<<<BATCH*TTYPE, 512, 0, stream>>>(AtCt, w2T16, bi2, ep, et, Ycat);
        k_gemm16<<<dim3(128, 1), 128, 0, stream>>>(Ycat, w3catT, comb, YROW, 256, 128);
        k_fused_update<<<NSLOT/16, 256, 0, stream>>>(comb, lu_g, lu_b, wu1T, bu1, wu2T, bu2, h, hout);
    }
}